// Round 2
// baseline (647.041 us; speedup 1.0000x reference)
//
#include <hip/hip_runtime.h>
#include <math.h>

#define N_ 64
#define C_ 384
#define L_ 3136   // 56*56
#define M_ 16
#define D_ 384

// ---------------------------------------------------------------------------
// K1: qs[n][c][m] = (sum_d x[n][m][d] * Wq[c][d] + bq[c]) * (1/sqrt(C))
// lane = c; x reads are wave-uniform; Wq row-streamed per lane.
// ---------------------------------------------------------------------------
__global__ __launch_bounds__(128) void k1_qproj(const float* __restrict__ x,
                                                const float* __restrict__ Wq,
                                                const float* __restrict__ bq,
                                                float* __restrict__ qs) {
    const int n = blockIdx.x;
    const int c = blockIdx.y * 128 + threadIdx.x;   // 3*128 = 384 exact
    const float4* __restrict__ wrow = (const float4*)(Wq + (size_t)c * D_);
    const float4* __restrict__ xn   = (const float4*)(x + (size_t)n * M_ * D_);
    float acc[M_];
#pragma unroll
    for (int m = 0; m < M_; ++m) acc[m] = 0.f;
    for (int dq = 0; dq < D_ / 4; ++dq) {
        const float4 wv = wrow[dq];
#pragma unroll
        for (int m = 0; m < M_; ++m) {
            const float4 xv = xn[m * (D_ / 4) + dq];   // wave-uniform
            acc[m] += wv.x * xv.x + wv.y * xv.y + wv.z * xv.z + wv.w * xv.w;
        }
    }
    const float rs = 0.05103103630798287f;  // 1/sqrt(384)
    const float b = bq[c];
    float* qout = qs + ((size_t)n * C_ + c) * M_;
#pragma unroll
    for (int m = 0; m < M_; ++m) qout[m] = (acc[m] + b) * rs;
}

// ---------------------------------------------------------------------------
// K2: scores[n][m][l] = sum_c qs[n][c][m] * lf[n][c][l]
// lane = l-pair (coalesced float2 along l); qs[c][0:16] wave-uniform per c.
// grid (64 n, 7 s) covering 448 l's per block; 224 active threads.
// ---------------------------------------------------------------------------
__global__ __launch_bounds__(256) void k2_scores(const float* __restrict__ lf,
                                                 const float* __restrict__ qs,
                                                 float* __restrict__ scores) {
    const int n = blockIdx.x;
    const int s = blockIdx.y;            // 0..6
    const int t = threadIdx.x;
    const bool active = (t < 224);
    const int l0 = s * 448 + (active ? t : 0) * 2;
    const float* __restrict__ lfn = lf + (size_t)n * C_ * L_;
    const float* __restrict__ qn  = qs + (size_t)n * C_ * M_;
    float accx[M_], accy[M_];
#pragma unroll
    for (int m = 0; m < M_; ++m) { accx[m] = 0.f; accy[m] = 0.f; }
    if (active) {
#pragma unroll 4
        for (int c = 0; c < C_; ++c) {
            const float2 lv = *(const float2*)(lfn + (size_t)c * L_ + l0);
            const float* __restrict__ qv = qn + c * M_;   // wave-uniform 64B
#pragma unroll
            for (int m = 0; m < M_; ++m) {
                accx[m] += qv[m] * lv.x;
                accy[m] += qv[m] * lv.y;
            }
        }
        float* sn = scores + (size_t)n * M_ * L_;
#pragma unroll
        for (int m = 0; m < M_; ++m) {
            *(float2*)(sn + (size_t)m * L_ + l0) = make_float2(accx[m], accy[m]);
        }
    }
}

// ---------------------------------------------------------------------------
// K3: in-place softmax over each scores[n][m][:] row. 1 wave per row.
// ---------------------------------------------------------------------------
__global__ __launch_bounds__(64) void k3_softmax(float* __restrict__ scores) {
    float* row = scores + (size_t)blockIdx.x * L_;   // blockIdx.x = n*16+m
    const int t = threadIdx.x;
    float lmax = -1e30f;
    for (int i = t; i < L_ / 4; i += 64) {
        const float4 v = ((const float4*)row)[i];
        lmax = fmaxf(lmax, fmaxf(fmaxf(v.x, v.y), fmaxf(v.z, v.w)));
    }
#pragma unroll
    for (int o = 32; o > 0; o >>= 1) lmax = fmaxf(lmax, __shfl_xor(lmax, o, 64));
    float lsum = 0.f;
    for (int i = t; i < L_ / 4; i += 64) {
        const float4 v = ((const float4*)row)[i];
        lsum += expf(v.x - lmax) + expf(v.y - lmax) +
                expf(v.z - lmax) + expf(v.w - lmax);
    }
#pragma unroll
    for (int o = 32; o > 0; o >>= 1) lsum += __shfl_xor(lsum, o, 64);
    const float inv = 1.0f / lsum;
    for (int i = t; i < L_ / 4; i += 64) {
        float4 v = ((const float4*)row)[i];
        v.x = expf(v.x - lmax) * inv;
        v.y = expf(v.y - lmax) * inv;
        v.z = expf(v.z - lmax) * inv;
        v.w = expf(v.w - lmax) * inv;
        ((float4*)row)[i] = v;
    }
}

// ---------------------------------------------------------------------------
// K4: fusionP[n][s][m][c] = sum_{l in split s} attn[n][m][l] * lf[n][c][l]
// lane = c (per-lane sequential row streaming of lf, 16B/iter);
// attn[0:16][l-quad] wave-uniform. grid (64 n, 8 s), 392 l's per split.
// ---------------------------------------------------------------------------
__global__ __launch_bounds__(384) void k4_fusion(const float* __restrict__ lf,
                                                 const float* __restrict__ attn,
                                                 float* __restrict__ fusionP) {
    const int n = blockIdx.x;
    const int s = blockIdx.y;        // 0..7
    const int c = threadIdx.x;       // 0..383
    const float* __restrict__ lrow = lf + ((size_t)n * C_ + c) * L_;
    const float* __restrict__ an   = attn + (size_t)n * M_ * L_;
    float acc[M_];
#pragma unroll
    for (int m = 0; m < M_; ++m) acc[m] = 0.f;
    const int l0 = s * 392;
#pragma unroll 2
    for (int lq = 0; lq < 98; ++lq) {
        const int l = l0 + lq * 4;
        const float4 lv = *(const float4*)(lrow + l);
#pragma unroll
        for (int m = 0; m < M_; ++m) {
            const float4 av = *(const float4*)(an + (size_t)m * L_ + l); // uniform
            acc[m] += av.x * lv.x + av.y * lv.y + av.z * lv.z + av.w * lv.w;
        }
    }
    float* fp = fusionP + ((size_t)(n * 8 + s) * M_) * C_;
#pragma unroll
    for (int m = 0; m < M_; ++m) fp[m * C_ + c] = acc[m];   // coalesced in c
}

// ---------------------------------------------------------------------------
// K4b: fusionP[n][0][m][c] += sum_{s>=1} fusionP[n][s][m][c]  (in-place)
// ---------------------------------------------------------------------------
__global__ __launch_bounds__(256) void k4b_reduce(float* __restrict__ fusionP) {
    const int i = blockIdx.x * 256 + threadIdx.x;   // 1536*256 = 393216 exact
    const int n = i / (M_ * C_);
    const int mc = i % (M_ * C_);
    float* p = fusionP + (size_t)n * 8 * M_ * C_ + mc;
    float v = p[0];
#pragma unroll
    for (int s2 = 1; s2 < 8; ++s2) v += p[s2 * M_ * C_];
    p[0] = v;
}

// ---------------------------------------------------------------------------
// K5: out[n][m][d] = sum_c fusion[n][m][c]*Wu[d][c] + bu[d] + x[n][m][d]
// fusion = fusionP[n][0][.][.]; lane = d, fusion reads wave-uniform.
// ---------------------------------------------------------------------------
__global__ __launch_bounds__(128) void k5_out(const float* __restrict__ fusionP,
                                              const float* __restrict__ Wu,
                                              const float* __restrict__ bu,
                                              const float* __restrict__ x,
                                              float* __restrict__ out) {
    const int n = blockIdx.x;
    const int d = blockIdx.y * 128 + threadIdx.x;   // 3*128 = 384 exact
    const float4* __restrict__ wrow = (const float4*)(Wu + (size_t)d * C_);
    const float4* __restrict__ fn   = (const float4*)(fusionP + (size_t)n * 8 * M_ * C_);
    float acc[M_];
#pragma unroll
    for (int m = 0; m < M_; ++m) acc[m] = 0.f;
    for (int cq = 0; cq < C_ / 4; ++cq) {
        const float4 wv = wrow[cq];
#pragma unroll
        for (int m = 0; m < M_; ++m) {
            const float4 fv = fn[m * (C_ / 4) + cq];   // wave-uniform
            acc[m] += wv.x * fv.x + wv.y * fv.y + wv.z * fv.z + wv.w * fv.w;
        }
    }
    const float b = bu[d];
#pragma unroll
    for (int m = 0; m < M_; ++m) {
        const size_t o = ((size_t)n * M_ + m) * D_ + d;
        out[o] = acc[m] + b + x[o];
    }
}

// ---------------------------------------------------------------------------
extern "C" void kernel_launch(void* const* d_in, const int* in_sizes, int n_in,
                              void* d_out, int out_size, void* d_ws, size_t ws_size,
                              hipStream_t stream) {
    const float* lf = (const float*)d_in[0];   // [64,384,56,56]
    const float* x  = (const float*)d_in[1];   // [64,16,384]
    const float* Wq = (const float*)d_in[2];   // [384,384]
    const float* bq = (const float*)d_in[3];   // [384]
    const float* Wu = (const float*)d_in[4];   // [384,384]
    const float* bu = (const float*)d_in[5];   // [384]
    float* out = (float*)d_out;

    float* ws      = (float*)d_ws;
    float* qs      = ws;                    // [64][384][16]    = 393216 floats
    float* scores  = qs + 393216;           // [64][16][3136]   = 3211264 floats
    float* fusionP = scores + 3211264;      // [64][8][16][384] = 3145728 floats
                                            // total 6,750,208 floats = 25.8 MB... wait
                                            // 393216+3211264+3145728 = 6750208 -> 27.0 MB? No:
                                            // 6,750,208 * 4 B = 25.75 MB of ws used.

    k1_qproj  <<<dim3(64, 3), 128, 0, stream>>>(x, Wq, bq, qs);
    k2_scores <<<dim3(64, 7), 256, 0, stream>>>(lf, qs, scores);
    k3_softmax<<<1024, 64, 0, stream>>>(scores);
    k4_fusion <<<dim3(64, 8), 384, 0, stream>>>(lf, scores, fusionP);
    k4b_reduce<<<1536, 256, 0, stream>>>(fusionP);
    k5_out    <<<dim3(64, 3), 128, 0, stream>>>(fusionP, Wu, bu, x, out);
}